// Round 1
// baseline (621.189 us; speedup 1.0000x reference)
//
#include <hip/hip_runtime.h>
#include <hip/hip_bf16.h>
#include <stdint.h>

#define Bb   8
#define Tt   2048
#define Cdim 1024
#define BT   16384   // Bb*Tt

typedef __attribute__((ext_vector_type(4))) float f32x4;
typedef __attribute__((ext_vector_type(8))) short bf16x8;

__device__ inline short f2bs(float f) {
    union { __hip_bfloat16 h; short s; } u;
    u.h = __float2bfloat16(f);
    return u.s;
}
__device__ inline float bs2f(short s) {
    union { short s; __hip_bfloat16 h; } u;
    u.s = s;
    return __bfloat162float(u.h);
}

#define GLOAD_LDS16(g, l) __builtin_amdgcn_global_load_lds( \
    (const __attribute__((address_space(1))) void*)(g),     \
    (__attribute__((address_space(3))) void*)(l), 16, 0, 0)

// ---------------------------------------------------------------------------
// prep_x: xmix[z][m][c] = lerp(x_prev, x, mix_z)  (bf16), z in {k,v,r}
// time_shift: row t reads x[t-1], zeros at t==0.
// ---------------------------------------------------------------------------
__global__ __launch_bounds__(256) void prep_x(
    const float* __restrict__ x,
    const float* __restrict__ mk,
    const float* __restrict__ mv,
    const float* __restrict__ mr,
    short* __restrict__ xmix)
{
    int idx = blockIdx.x * 256 + threadIdx.x;   // [0, BT*Cdim/8)
    int c8  = idx & (Cdim / 8 - 1);
    int m   = idx >> 7;                          // Cdim/8 == 128
    int c0  = c8 << 3;
    int t   = m & (Tt - 1);

    float xs[8], ps[8];
    const float4* xp = (const float4*)(x + (size_t)m * Cdim + c0);
    float4 xa = xp[0], xb = xp[1];
    xs[0]=xa.x; xs[1]=xa.y; xs[2]=xa.z; xs[3]=xa.w;
    xs[4]=xb.x; xs[5]=xb.y; xs[6]=xb.z; xs[7]=xb.w;
    if (t != 0) {
        const float4* pp = (const float4*)(x + (size_t)(m - 1) * Cdim + c0);
        float4 pa = pp[0], pb = pp[1];
        ps[0]=pa.x; ps[1]=pa.y; ps[2]=pa.z; ps[3]=pa.w;
        ps[4]=pb.x; ps[5]=pb.y; ps[6]=pb.z; ps[7]=pb.w;
    } else {
        #pragma unroll
        for (int j = 0; j < 8; ++j) ps[j] = 0.f;
    }

    const float* mixes[3] = {mk, mv, mr};
    #pragma unroll
    for (int z = 0; z < 3; ++z) {
        const float4* mp = (const float4*)(mixes[z] + c0);
        float4 ma = mp[0], mb = mp[1];
        float mm[8];
        mm[0]=ma.x; mm[1]=ma.y; mm[2]=ma.z; mm[3]=ma.w;
        mm[4]=mb.x; mm[5]=mb.y; mm[6]=mb.z; mm[7]=mb.w;
        bf16x8 o;
        #pragma unroll
        for (int j = 0; j < 8; ++j)
            o[j] = f2bs(ps[j] + mm[j] * (xs[j] - ps[j]));
        *(bf16x8*)(xmix + (size_t)z * BT * Cdim + (size_t)m * Cdim + c0) = o;
    }
}

// ---------------------------------------------------------------------------
// prep_w: Wk|Wv|Wr|Wo f32 -> bf16, concatenated [4][C][C]
// ---------------------------------------------------------------------------
__global__ __launch_bounds__(256) void prep_w(
    const float* __restrict__ Wk, const float* __restrict__ Wv,
    const float* __restrict__ Wr, const float* __restrict__ Wo,
    short* __restrict__ wbf)
{
    int idx = blockIdx.x * 256 + threadIdx.x;       // [0, 4*C*C/8)
    int z   = idx >> 17;                            // C*C/8 == 131072
    int r   = idx & (Cdim * Cdim / 8 - 1);
    const float* src = (z == 0) ? Wk : (z == 1) ? Wv : (z == 2) ? Wr : Wo;
    const float4* sp = (const float4*)(src + (size_t)r * 8);
    float4 a = sp[0], b = sp[1];
    float v[8] = {a.x, a.y, a.z, a.w, b.x, b.y, b.z, b.w};
    bf16x8 o;
    #pragma unroll
    for (int j = 0; j < 8; ++j) o[j] = f2bs(v[j]);
    *(bf16x8*)(wbf + (size_t)z * Cdim * Cdim + (size_t)r * 8) = o;
}

// ---------------------------------------------------------------------------
// gemm_bt: C[m][n] = sum_k A[m][k] * B[n][k]   (A,B bf16 row-major, f32 acc)
// 128x128 tile, BK=64, 4 waves (2x2, 64x64 each), global_load_lds staging,
// 2-barrier K-loop (m97 structure).
// ---------------------------------------------------------------------------
template<int STORE_BF16>
__global__ __launch_bounds__(256) void gemm_bt(
    const short* __restrict__ A,   // [M][K]
    const short* __restrict__ Bm,  // [N][K]
    void* __restrict__ Cout,       // [M][N]
    int M, int N, int K)
{
    __shared__ __align__(16) short a_lds[128 * 64];
    __shared__ __align__(16) short b_lds[128 * 64];

    int tid  = threadIdx.x;
    int lane = tid & 63;
    int wv   = tid >> 6;
    int wm   = wv >> 1, wn = wv & 1;
    int m0 = blockIdx.y * 128;
    int n0 = blockIdx.x * 128;

    f32x4 acc[4][4] = {};

    for (int k0 = 0; k0 < K; k0 += 64) {
        // stage A,B tiles: 128 rows x 64 cols bf16 each; 16B per thread x4
        #pragma unroll
        for (int i = 0; i < 4; ++i) {
            int chunk = tid + i * 256;         // 0..1023, = row*8 + colchunk
            int row = chunk >> 3;
            int cc  = chunk & 7;
            const short* ga = A  + (size_t)(m0 + row) * K + k0 + cc * 8;
            GLOAD_LDS16(ga, a_lds + chunk * 8);
            const short* gb = Bm + (size_t)(n0 + row) * K + k0 + cc * 8;
            GLOAD_LDS16(gb, b_lds + chunk * 8);
        }
        __syncthreads();   // drains vmcnt before barrier (compiler-inserted)

        #pragma unroll
        for (int kk = 0; kk < 2; ++kk) {
            bf16x8 af[4], bf[4];
            #pragma unroll
            for (int i = 0; i < 4; ++i) {
                int ar = wm * 64 + i * 16 + (lane & 15);
                af[i] = *(const bf16x8*)(a_lds + ar * 64 + kk * 32 + (lane >> 4) * 8);
                int br = wn * 64 + i * 16 + (lane & 15);
                bf[i] = *(const bf16x8*)(b_lds + br * 64 + kk * 32 + (lane >> 4) * 8);
            }
            #pragma unroll
            for (int mi = 0; mi < 4; ++mi)
                #pragma unroll
                for (int ni = 0; ni < 4; ++ni)
                    acc[mi][ni] = __builtin_amdgcn_mfma_f32_16x16x32_bf16(
                        af[mi], bf[ni], acc[mi][ni], 0, 0, 0);
        }
        __syncthreads();
    }

    // epilogue: C/D layout col = lane&15, row = (lane>>4)*4 + r  [m89]
    int col   = n0 + wn * 64 + (lane & 15);
    int rbase = m0 + wm * 64 + ((lane >> 4) << 2);
    #pragma unroll
    for (int mi = 0; mi < 4; ++mi) {
        #pragma unroll
        for (int ni = 0; ni < 4; ++ni) {
            #pragma unroll
            for (int r = 0; r < 4; ++r) {
                int row = rbase + mi * 16 + r;
                int cc  = col + ni * 16;
                if (STORE_BF16)
                    ((short*)Cout)[(size_t)row * N + cc] = f2bs(acc[mi][ni][r]);
                else
                    ((float*)Cout)[(size_t)row * N + cc] = acc[mi][ni][r];
            }
        }
    }
}

// ---------------------------------------------------------------------------
// wkv_sig: numerically-stable WKV scan per (b,c) chain + sigmoid(r) gate.
// One thread per chain; f32 state, bf16 I/O.
// ---------------------------------------------------------------------------
__global__ __launch_bounds__(64) void wkv_sig(
    const short* __restrict__ kb, const short* __restrict__ vb,
    const short* __restrict__ rb,
    const float* __restrict__ w, const float* __restrict__ u,
    short* __restrict__ rwkv)
{
    int idx = blockIdx.x * 64 + threadIdx.x;    // [0, Bb*Cdim)
    int c = idx & (Cdim - 1);
    int b = idx >> 10;
    float wexp = -__expf(w[c]);
    float uu   = u[c];
    float p = 0.f, q = 0.f, o = -1e30f;
    size_t base = (size_t)b * Tt * Cdim + c;

    #pragma unroll 4
    for (int t = 0; t < Tt; ++t) {
        size_t off = base + (size_t)t * Cdim;
        float kt = bs2f(kb[off]);
        float vt = bs2f(vb[off]);
        float rt = bs2f(rb[off]);

        float uk = uu + kt;
        float no = fmaxf(o, uk);
        float Aa = __expf(o - no);
        float Bc = __expf(uk - no);
        float out = (Aa * p + Bc * vt) / (Aa * q + Bc);

        float wo  = wexp + o;
        float no2 = fmaxf(wo, kt);
        float A2  = __expf(wo - no2);
        float B2  = __expf(kt - no2);
        p = A2 * p + B2 * vt;
        q = A2 * q + B2;
        o = no2;

        float sr = 1.f / (1.f + __expf(-rt));
        rwkv[off] = f2bs(sr * out);
    }
}

// ---------------------------------------------------------------------------
extern "C" void kernel_launch(void* const* d_in, const int* in_sizes, int n_in,
                              void* d_out, int out_size, void* d_ws, size_t ws_size,
                              hipStream_t stream)
{
    const float* x    = (const float*)d_in[0];
    const float* w    = (const float*)d_in[1];
    const float* u    = (const float*)d_in[2];
    const float* mixk = (const float*)d_in[3];
    const float* mixv = (const float*)d_in[4];
    const float* mixr = (const float*)d_in[5];
    const float* Wk   = (const float*)d_in[6];
    const float* Wv   = (const float*)d_in[7];
    const float* Wr   = (const float*)d_in[8];
    const float* Wo   = (const float*)d_in[9];

    const size_t SLAB = (size_t)BT * Cdim;           // 16.78M elements
    char* ws = (char*)d_ws;
    short* xmix = (short*)ws;                        // 3 slabs bf16 = 96 MiB
    short* wbf  = (short*)(ws + 3 * SLAB * 2);       // 4*C*C bf16 = 8 MiB
    short* rbuf = (short*)(ws + 3 * SLAB * 2 + (size_t)4 * Cdim * Cdim * 2); // 32 MiB
    short* rwkv = (short*)ws;                        // reuses dead xmix slab 0
    short* kbuf = (short*)d_out;                     // k,v bf16 live in d_out
    short* vbuf = kbuf + SLAB;                       // exactly fills 64 MiB

    prep_x<<<BT * Cdim / 8 / 256, 256, 0, stream>>>(x, mixk, mixv, mixr, xmix);
    prep_w<<<4 * Cdim * Cdim / 8 / 256, 256, 0, stream>>>(Wk, Wv, Wr, Wo, wbf);

    dim3 g(Cdim / 128, BT / 128);
    gemm_bt<1><<<g, 256, 0, stream>>>(xmix,            wbf,                    kbuf, BT, Cdim, Cdim);
    gemm_bt<1><<<g, 256, 0, stream>>>(xmix + SLAB,     wbf + Cdim * Cdim,      vbuf, BT, Cdim, Cdim);
    gemm_bt<1><<<g, 256, 0, stream>>>(xmix + 2 * SLAB, wbf + 2 * Cdim * Cdim,  rbuf, BT, Cdim, Cdim);

    wkv_sig<<<Bb * Cdim / 64, 64, 0, stream>>>(kbuf, vbuf, rbuf, w, u, rwkv);

    gemm_bt<0><<<g, 256, 0, stream>>>(rwkv, wbf + 3 * Cdim * Cdim, (float*)d_out, BT, Cdim, Cdim);
}

// Round 2
// 327.013 us; speedup vs baseline: 1.8996x; 1.8996x over previous
//
#include <hip/hip_runtime.h>
#include <hip/hip_bf16.h>
#include <stdint.h>

#define Bb   8
#define Tt   2048
#define Cdim 1024
#define BT   16384   // Bb*Tt

// chunked WKV scan geometry
#define NC   32            // chunks per chain
#define LCH  64            // Tt / NC
#define CSUB 32            // channels per block

typedef __attribute__((ext_vector_type(4))) float f32x4;
typedef __attribute__((ext_vector_type(8))) short bf16x8;

__device__ inline short f2bs(float f) {
    union { __hip_bfloat16 h; short s; } u;
    u.h = __float2bfloat16(f);
    return u.s;
}
__device__ inline float bs2f(short s) {
    union { short s; __hip_bfloat16 h; } u;
    u.s = s;
    return __bfloat162float(u.h);
}

#define GLOAD_LDS16(g, l) __builtin_amdgcn_global_load_lds( \
    (const __attribute__((address_space(1))) void*)(g),     \
    (__attribute__((address_space(3))) void*)(l), 16, 0, 0)

// ---------------------------------------------------------------------------
// prep_x: xmix[z][m][c] = lerp(x_prev, x, mix_z)  (bf16), z in {k,v,r}
// ---------------------------------------------------------------------------
__global__ __launch_bounds__(256) void prep_x(
    const float* __restrict__ x,
    const float* __restrict__ mk,
    const float* __restrict__ mv,
    const float* __restrict__ mr,
    short* __restrict__ xmix)
{
    int idx = blockIdx.x * 256 + threadIdx.x;   // [0, BT*Cdim/8)
    int c8  = idx & (Cdim / 8 - 1);
    int m   = idx >> 7;                          // Cdim/8 == 128
    int c0  = c8 << 3;
    int t   = m & (Tt - 1);

    float xs[8], ps[8];
    const float4* xp = (const float4*)(x + (size_t)m * Cdim + c0);
    float4 xa = xp[0], xb = xp[1];
    xs[0]=xa.x; xs[1]=xa.y; xs[2]=xa.z; xs[3]=xa.w;
    xs[4]=xb.x; xs[5]=xb.y; xs[6]=xb.z; xs[7]=xb.w;
    if (t != 0) {
        const float4* pp = (const float4*)(x + (size_t)(m - 1) * Cdim + c0);
        float4 pa = pp[0], pb = pp[1];
        ps[0]=pa.x; ps[1]=pa.y; ps[2]=pa.z; ps[3]=pa.w;
        ps[4]=pb.x; ps[5]=pb.y; ps[6]=pb.z; ps[7]=pb.w;
    } else {
        #pragma unroll
        for (int j = 0; j < 8; ++j) ps[j] = 0.f;
    }

    const float* mixes[3] = {mk, mv, mr};
    #pragma unroll
    for (int z = 0; z < 3; ++z) {
        const float4* mp = (const float4*)(mixes[z] + c0);
        float4 ma = mp[0], mb = mp[1];
        float mm[8];
        mm[0]=ma.x; mm[1]=ma.y; mm[2]=ma.z; mm[3]=ma.w;
        mm[4]=mb.x; mm[5]=mb.y; mm[6]=mb.z; mm[7]=mb.w;
        bf16x8 o;
        #pragma unroll
        for (int j = 0; j < 8; ++j)
            o[j] = f2bs(ps[j] + mm[j] * (xs[j] - ps[j]));
        *(bf16x8*)(xmix + (size_t)z * BT * Cdim + (size_t)m * Cdim + c0) = o;
    }
}

// ---------------------------------------------------------------------------
// prep_w: Wk|Wv|Wr|Wo f32 -> bf16, concatenated [4][C][C]
// ---------------------------------------------------------------------------
__global__ __launch_bounds__(256) void prep_w(
    const float* __restrict__ Wk, const float* __restrict__ Wv,
    const float* __restrict__ Wr, const float* __restrict__ Wo,
    short* __restrict__ wbf)
{
    int idx = blockIdx.x * 256 + threadIdx.x;       // [0, 4*C*C/8)
    int z   = idx >> 17;                            // C*C/8 == 131072
    int r   = idx & (Cdim * Cdim / 8 - 1);
    const float* src = (z == 0) ? Wk : (z == 1) ? Wv : (z == 2) ? Wr : Wo;
    const float4* sp = (const float4*)(src + (size_t)r * 8);
    float4 a = sp[0], b = sp[1];
    float v[8] = {a.x, a.y, a.z, a.w, b.x, b.y, b.z, b.w};
    bf16x8 o;
    #pragma unroll
    for (int j = 0; j < 8; ++j) o[j] = f2bs(v[j]);
    *(bf16x8*)(wbf + (size_t)z * Cdim * Cdim + (size_t)r * 8) = o;
}

// ---------------------------------------------------------------------------
// gemm_bt: C[m][n] = sum_k A[m][k] * B[n][k]   (A,B bf16 row-major, f32 acc)
// 128x128 tile, BK=64, 4 waves (2x2, 64x64 each), global_load_lds staging.
// ---------------------------------------------------------------------------
template<int STORE_BF16>
__global__ __launch_bounds__(256) void gemm_bt(
    const short* __restrict__ A,   // [M][K]
    const short* __restrict__ Bm,  // [N][K]
    void* __restrict__ Cout,       // [M][N]
    int M, int N, int K)
{
    __shared__ __align__(16) short a_lds[128 * 64];
    __shared__ __align__(16) short b_lds[128 * 64];

    int tid  = threadIdx.x;
    int lane = tid & 63;
    int wv   = tid >> 6;
    int wm   = wv >> 1, wn = wv & 1;
    int m0 = blockIdx.y * 128;
    int n0 = blockIdx.x * 128;

    f32x4 acc[4][4] = {};

    for (int k0 = 0; k0 < K; k0 += 64) {
        #pragma unroll
        for (int i = 0; i < 4; ++i) {
            int chunk = tid + i * 256;         // 0..1023, = row*8 + colchunk
            int row = chunk >> 3;
            int cc  = chunk & 7;
            const short* ga = A  + (size_t)(m0 + row) * K + k0 + cc * 8;
            GLOAD_LDS16(ga, a_lds + chunk * 8);
            const short* gb = Bm + (size_t)(n0 + row) * K + k0 + cc * 8;
            GLOAD_LDS16(gb, b_lds + chunk * 8);
        }
        __syncthreads();

        #pragma unroll
        for (int kk = 0; kk < 2; ++kk) {
            bf16x8 af[4], bf[4];
            #pragma unroll
            for (int i = 0; i < 4; ++i) {
                int ar = wm * 64 + i * 16 + (lane & 15);
                af[i] = *(const bf16x8*)(a_lds + ar * 64 + kk * 32 + (lane >> 4) * 8);
                int br = wn * 64 + i * 16 + (lane & 15);
                bf[i] = *(const bf16x8*)(b_lds + br * 64 + kk * 32 + (lane >> 4) * 8);
            }
            #pragma unroll
            for (int mi = 0; mi < 4; ++mi)
                #pragma unroll
                for (int ni = 0; ni < 4; ++ni)
                    acc[mi][ni] = __builtin_amdgcn_mfma_f32_16x16x32_bf16(
                        af[mi], bf[ni], acc[mi][ni], 0, 0, 0);
        }
        __syncthreads();
    }

    int col   = n0 + wn * 64 + (lane & 15);
    int rbase = m0 + wm * 64 + ((lane >> 4) << 2);
    #pragma unroll
    for (int mi = 0; mi < 4; ++mi) {
        #pragma unroll
        for (int ni = 0; ni < 4; ++ni) {
            #pragma unroll
            for (int r = 0; r < 4; ++r) {
                int row = rbase + mi * 16 + r;
                int cc  = col + ni * 16;
                if (STORE_BF16)
                    ((short*)Cout)[(size_t)row * N + cc] = f2bs(acc[mi][ni][r]);
                else
                    ((float*)Cout)[(size_t)row * N + cc] = acc[mi][ni][r];
            }
        }
    }
}

// ---------------------------------------------------------------------------
// wkv_chunked: chunked-parallel stable WKV scan + sigmoid(r) gate.
// The stable state (p,q,o) represents P=p*e^o, Q=q*e^o of the linear
// recurrence P <- e^wexp * P + e^k * v; composition is associative:
//   decay over L steps: o += L*wexp
//   combine(s1, s2):    no=max(o1,o2); p=e^{o1-no}p1+e^{o2-no}p2; (q same)
// Block: CSUB=32 channels x NC=32 chunks = 1024 threads; grid = B * C/CSUB.
// ---------------------------------------------------------------------------
__global__ __launch_bounds__(1024) void wkv_chunked(
    const short* __restrict__ kb, const short* __restrict__ vb,
    const short* __restrict__ rb,
    const float* __restrict__ w, const float* __restrict__ u,
    short* __restrict__ rwkv)
{
    __shared__ float sp[NC][CSUB];
    __shared__ float sq[NC][CSUB];
    __shared__ float so[NC][CSUB];

    int tid = threadIdx.x;
    int cl  = tid & (CSUB - 1);
    int ch  = tid >> 5;                 // chunk index 0..NC-1
    int b   = blockIdx.x >> 5;          // grid = Bb * (Cdim/CSUB) = 8*32
    int cg  = blockIdx.x & 31;
    int c   = cg * CSUB + cl;

    float wexp = -__expf(w[c]);
    float uu   = u[c];
    size_t coff = (size_t)b * Tt * Cdim + (size_t)(ch * LCH) * Cdim + c;

    // ---- phase 1: local chunk summary from zero state ----
    float p = 0.f, q = 0.f, o = -1e30f;
    #pragma unroll 8
    for (int t = 0; t < LCH; ++t) {
        size_t off = coff + (size_t)t * Cdim;
        float kt = bs2f(kb[off]);
        float vt = bs2f(vb[off]);
        float wo  = wexp + o;
        float no  = fmaxf(wo, kt);
        float A   = __expf(wo - no);
        float B2  = __expf(kt - no);
        p = A * p + B2 * vt;
        q = A * q + B2;
        o = no;
    }
    sp[ch][cl] = p; sq[ch][cl] = q; so[ch][cl] = o;
    __syncthreads();

    // ---- phase 2: exclusive combine-scan over chunks (1 thread / channel) ----
    if (tid < CSUB) {
        float Ld = wexp * (float)LCH;   // decay of o over a full chunk
        float cp = 0.f, cq = 0.f, co = -1e30f;
        for (int j = 0; j < NC; ++j) {
            float lp = sp[j][tid], lq = sq[j][tid], lo = so[j][tid];
            sp[j][tid] = cp; sq[j][tid] = cq; so[j][tid] = co;  // incoming state
            float od = co + Ld;
            float no = fmaxf(od, lo);
            float A  = __expf(od - no);
            float B2 = __expf(lo - no);
            cp = A * cp + B2 * lp;
            cq = A * cq + B2 * lq;
            co = no;
        }
    }
    __syncthreads();

    // ---- phase 3: outputs from incoming state ----
    p = sp[ch][cl]; q = sq[ch][cl]; o = so[ch][cl];
    #pragma unroll 4
    for (int t = 0; t < LCH; ++t) {
        size_t off = coff + (size_t)t * Cdim;
        float kt = bs2f(kb[off]);
        float vt = bs2f(vb[off]);
        float rt = bs2f(rb[off]);

        float uk  = uu + kt;
        float no  = fmaxf(o, uk);
        float Aa  = __expf(o - no);
        float Bc  = __expf(uk - no);
        float out = (Aa * p + Bc * vt) / (Aa * q + Bc);

        float wo  = wexp + o;
        float no2 = fmaxf(wo, kt);
        float A2  = __expf(wo - no2);
        float B2  = __expf(kt - no2);
        p = A2 * p + B2 * vt;
        q = A2 * q + B2;
        o = no2;

        float sr = 1.f / (1.f + __expf(-rt));
        rwkv[off] = f2bs(sr * out);
    }
}

// ---------------------------------------------------------------------------
extern "C" void kernel_launch(void* const* d_in, const int* in_sizes, int n_in,
                              void* d_out, int out_size, void* d_ws, size_t ws_size,
                              hipStream_t stream)
{
    const float* x    = (const float*)d_in[0];
    const float* w    = (const float*)d_in[1];
    const float* u    = (const float*)d_in[2];
    const float* mixk = (const float*)d_in[3];
    const float* mixv = (const float*)d_in[4];
    const float* mixr = (const float*)d_in[5];
    const float* Wk   = (const float*)d_in[6];
    const float* Wv   = (const float*)d_in[7];
    const float* Wr   = (const float*)d_in[8];
    const float* Wo   = (const float*)d_in[9];

    const size_t SLAB = (size_t)BT * Cdim;           // 16.78M elements
    char* ws = (char*)d_ws;
    short* xmix = (short*)ws;                        // 3 slabs bf16 = 96 MiB
    short* wbf  = (short*)(ws + 3 * SLAB * 2);       // 4*C*C bf16 = 8 MiB
    short* rbuf = (short*)(ws + 3 * SLAB * 2 + (size_t)4 * Cdim * Cdim * 2); // 32 MiB
    short* rwkv = (short*)ws;                        // reuses dead xmix slab 0
    short* kbuf = (short*)d_out;                     // k,v bf16 live in d_out
    short* vbuf = kbuf + SLAB;                       // exactly fills 64 MiB

    prep_x<<<BT * Cdim / 8 / 256, 256, 0, stream>>>(x, mixk, mixv, mixr, xmix);
    prep_w<<<4 * Cdim * Cdim / 8 / 256, 256, 0, stream>>>(Wk, Wv, Wr, Wo, wbf);

    dim3 g(Cdim / 128, BT / 128);
    gemm_bt<1><<<g, 256, 0, stream>>>(xmix,            wbf,                    kbuf, BT, Cdim, Cdim);
    gemm_bt<1><<<g, 256, 0, stream>>>(xmix + SLAB,     wbf + Cdim * Cdim,      vbuf, BT, Cdim, Cdim);
    gemm_bt<1><<<g, 256, 0, stream>>>(xmix + 2 * SLAB, wbf + 2 * Cdim * Cdim,  rbuf, BT, Cdim, Cdim);

    wkv_chunked<<<Bb * (Cdim / CSUB), 1024, 0, stream>>>(kbuf, vbuf, rbuf, w, u, rwkv);

    gemm_bt<0><<<g, 256, 0, stream>>>(rwkv, wbf + 3 * Cdim * Cdim, (float*)d_out, BT, Cdim, Cdim);
}

// Round 3
// 264.886 us; speedup vs baseline: 2.3451x; 1.2345x over previous
//
#include <hip/hip_runtime.h>
#include <hip/hip_bf16.h>
#include <stdint.h>

#define Bb   8
#define Tt   2048
#define Cdim 1024
#define BT   16384   // Bb*Tt

// chunked WKV scan geometry
#define NC   32            // chunks per chain
#define LCH  64            // Tt / NC
#define CSUB 32            // channels per block

typedef __attribute__((ext_vector_type(4))) float f32x4;
typedef __attribute__((ext_vector_type(8))) short bf16x8;

__device__ inline short f2bs(float f) {
    union { __hip_bfloat16 h; short s; } u;
    u.h = __float2bfloat16(f);
    return u.s;
}
__device__ inline float bs2f(short s) {
    union { short s; __hip_bfloat16 h; } u;
    u.s = s;
    return __bfloat162float(u.h);
}

#define GLOAD_LDS16(g, l) __builtin_amdgcn_global_load_lds( \
    (const __attribute__((address_space(1))) void*)(g),     \
    (__attribute__((address_space(3))) void*)(l), 16, 0, 0)

#define SBAR()      __builtin_amdgcn_s_barrier()
#define WAIT_LGKM0  asm volatile("s_waitcnt lgkmcnt(0)" ::: "memory")

// ---------------------------------------------------------------------------
// prep_x: xmix[z][m][c] = lerp(x_prev, x, mix_z)  (bf16), z in {k,v,r}
// ---------------------------------------------------------------------------
__global__ __launch_bounds__(256) void prep_x(
    const float* __restrict__ x,
    const float* __restrict__ mk,
    const float* __restrict__ mv,
    const float* __restrict__ mr,
    short* __restrict__ xmix)
{
    int idx = blockIdx.x * 256 + threadIdx.x;   // [0, BT*Cdim/8)
    int c8  = idx & (Cdim / 8 - 1);
    int m   = idx >> 7;                          // Cdim/8 == 128
    int c0  = c8 << 3;
    int t   = m & (Tt - 1);

    float xs[8], ps[8];
    const float4* xp = (const float4*)(x + (size_t)m * Cdim + c0);
    float4 xa = xp[0], xb = xp[1];
    xs[0]=xa.x; xs[1]=xa.y; xs[2]=xa.z; xs[3]=xa.w;
    xs[4]=xb.x; xs[5]=xb.y; xs[6]=xb.z; xs[7]=xb.w;
    if (t != 0) {
        const float4* pp = (const float4*)(x + (size_t)(m - 1) * Cdim + c0);
        float4 pa = pp[0], pb = pp[1];
        ps[0]=pa.x; ps[1]=pa.y; ps[2]=pa.z; ps[3]=pa.w;
        ps[4]=pb.x; ps[5]=pb.y; ps[6]=pb.z; ps[7]=pb.w;
    } else {
        #pragma unroll
        for (int j = 0; j < 8; ++j) ps[j] = 0.f;
    }

    const float* mixes[3] = {mk, mv, mr};
    #pragma unroll
    for (int z = 0; z < 3; ++z) {
        const float4* mp = (const float4*)(mixes[z] + c0);
        float4 ma = mp[0], mb = mp[1];
        float mm[8];
        mm[0]=ma.x; mm[1]=ma.y; mm[2]=ma.z; mm[3]=ma.w;
        mm[4]=mb.x; mm[5]=mb.y; mm[6]=mb.z; mm[7]=mb.w;
        bf16x8 o;
        #pragma unroll
        for (int j = 0; j < 8; ++j)
            o[j] = f2bs(ps[j] + mm[j] * (xs[j] - ps[j]));
        *(bf16x8*)(xmix + (size_t)z * BT * Cdim + (size_t)m * Cdim + c0) = o;
    }
}

// ---------------------------------------------------------------------------
// prep_w: Wk|Wv|Wr|Wo f32 -> bf16, concatenated [4][C][C]
// ---------------------------------------------------------------------------
__global__ __launch_bounds__(256) void prep_w(
    const float* __restrict__ Wk, const float* __restrict__ Wv,
    const float* __restrict__ Wr, const float* __restrict__ Wo,
    short* __restrict__ wbf)
{
    int idx = blockIdx.x * 256 + threadIdx.x;       // [0, 4*C*C/8)
    int z   = idx >> 17;                            // C*C/8 == 131072
    int r   = idx & (Cdim * Cdim / 8 - 1);
    const float* src = (z == 0) ? Wk : (z == 1) ? Wv : (z == 2) ? Wr : Wo;
    const float4* sp = (const float4*)(src + (size_t)r * 8);
    float4 a = sp[0], b = sp[1];
    float v[8] = {a.x, a.y, a.z, a.w, b.x, b.y, b.z, b.w};
    bf16x8 o;
    #pragma unroll
    for (int j = 0; j < 8; ++j) o[j] = f2bs(v[j]);
    *(bf16x8*)(wbf + (size_t)z * Cdim * Cdim + (size_t)r * 8) = o;
}

// ---------------------------------------------------------------------------
// gemm256: C[m][n] = sum_k A[m][k]*B[n][k], bf16 in, f32 acc.
// 256x256 tile, BK=32, 8 waves (2Mx4N), quad-buffered LDS (4 x 16KB x {A,B}),
// 2 phases per K-tile with counted vmcnt (T3+T4), LDS XOR-swizzle (T2),
// setprio around MFMA clusters (T5).
// Swizzle: 16B-chunk index ^= (row>>1)&3 (involution); applied on the global
// SOURCE address at stage time (global_load_lds writes linearly) and on the
// LDS read address (rule 21: both-sides-or-neither).
// MODE: 0 = f32 store, 1 = bf16 store, 2 = bf16 sigmoid store.
// ---------------------------------------------------------------------------
template<int MODE>
__global__ __launch_bounds__(512, 2) void gemm256(
    const short* __restrict__ A,   // [M][K]
    const short* __restrict__ Bm,  // [N][K]
    void* __restrict__ Cout,       // [M][N]
    int M, int N, int K)
{
    __shared__ __align__(16) short lds[65536];   // 128 KiB: 4 bufs x (A 8192 | B 8192)

    const int tid  = threadIdx.x;
    const int lane = tid & 63;
    const int wv   = tid >> 6;
    const int wm   = wv >> 2, wn = wv & 3;       // 2 x 4 waves
    const int m0 = blockIdx.y * 256;
    const int n0 = blockIdx.x * 256;
    const int NT = K >> 5;                       // K-tiles of 32

    f32x4 acc[8][4] = {};

    // per-lane fragment offsets within a buffer (shorts), swizzled
    int a_off[8], b_off[4];
    #pragma unroll
    for (int i = 0; i < 8; ++i) {
        int r = wm * 128 + i * 16 + (lane & 15);
        a_off[i] = r * 32 + ((((lane >> 4) ^ ((r >> 1) & 3))) << 3);
    }
    #pragma unroll
    for (int j = 0; j < 4; ++j) {
        int r = wn * 64 + j * 16 + (lane & 15);
        b_off[j] = r * 32 + ((((lane >> 4) ^ ((r >> 1) & 3))) << 3);
    }

    // stage part p (0,1 = A halves; 2,3 = B halves) of K-tile tt.
    // LDS dest is linear (wave-uniform base + lane*16); global source chunk
    // is pre-swizzled so reads with swizzled addresses see linear data.
    auto STAGE = [&](int tt, int p) {
        int row = ((p & 1) << 7) + (tid >> 2);          // 0..255 within tile
        int cc  = (tid & 3) ^ ((row >> 1) & 3);
        const short* g = ((p < 2) ? (A + (size_t)(m0 + row) * K)
                                  : (Bm + (size_t)(n0 + row) * K))
                         + (tt << 5) + (cc << 3);
        short* l = lds + ((tt & 3) << 14) + ((p < 2) ? 0 : 8192)
                       + ((p & 1) << 12) + tid * 8;
        GLOAD_LDS16(g, l);
    };

    // prologue: stage tiles 0 and 1 (8 loads/thread), wait tile0, barrier
    #pragma unroll
    for (int p = 0; p < 4; ++p) STAGE(0, p);
    #pragma unroll
    for (int p = 0; p < 4; ++p) STAGE(1, p);
    asm volatile("s_waitcnt vmcnt(4)" ::: "memory");
    SBAR();

    #pragma unroll 1
    for (int kt = 0; kt < NT; ++kt) {
        const short* la = lds + ((kt & 3) << 14);
        const short* lb = la + 8192;
        const bool st = (kt + 2) < NT;

        // ---- phase 0: A frags 0-3 + all B frags; MFMA m0-3 x n0-3 ----
        bf16x8 afr[4], bfr[4];
        #pragma unroll
        for (int i = 0; i < 4; ++i) afr[i] = *(const bf16x8*)(la + a_off[i]);
        #pragma unroll
        for (int j = 0; j < 4; ++j) bfr[j] = *(const bf16x8*)(lb + b_off[j]);
        if (st) { STAGE(kt + 2, 0); STAGE(kt + 2, 1); }
        SBAR();
        WAIT_LGKM0;
        __builtin_amdgcn_sched_barrier(0);
        __builtin_amdgcn_s_setprio(1);
        #pragma unroll
        for (int i = 0; i < 4; ++i)
            #pragma unroll
            for (int j = 0; j < 4; ++j)
                acc[i][j] = __builtin_amdgcn_mfma_f32_16x16x32_bf16(
                    afr[i], bfr[j], acc[i][j], 0, 0, 0);
        __builtin_amdgcn_s_setprio(0);
        SBAR();

        // ---- phase 1: A frags 4-7; MFMA m4-7 x n0-3 ----
        bf16x8 af2[4];
        #pragma unroll
        for (int i = 0; i < 4; ++i) af2[i] = *(const bf16x8*)(la + a_off[i + 4]);
        if (st) { STAGE(kt + 2, 2); STAGE(kt + 2, 3); }
        SBAR();
        WAIT_LGKM0;
        __builtin_amdgcn_sched_barrier(0);
        __builtin_amdgcn_s_setprio(1);
        #pragma unroll
        for (int i = 0; i < 4; ++i)
            #pragma unroll
            for (int j = 0; j < 4; ++j)
                acc[i + 4][j] = __builtin_amdgcn_mfma_f32_16x16x32_bf16(
                    af2[i], bfr[j], acc[i + 4][j], 0, 0, 0);
        __builtin_amdgcn_s_setprio(0);
        // counted vmcnt: tile kt+1 (staged during kt-1) must be complete;
        // the 4 loads issued this tile (for kt+2) stay in flight.
        if (kt < NT - 2) { asm volatile("s_waitcnt vmcnt(4)" ::: "memory"); }
        else             { asm volatile("s_waitcnt vmcnt(0)" ::: "memory"); }
        SBAR();
    }

    // epilogue: C/D layout col = lane&15, row = (lane>>4)*4 + r  [m89]
    int col0 = n0 + wn * 64 + (lane & 15);
    int row0 = m0 + wm * 128 + ((lane >> 4) << 2);
    #pragma unroll
    for (int i = 0; i < 8; ++i) {
        #pragma unroll
        for (int j = 0; j < 4; ++j) {
            #pragma unroll
            for (int r = 0; r < 4; ++r) {
                int row = row0 + i * 16 + r;
                int cc  = col0 + j * 16;
                float vvv = acc[i][j][r];
                if (MODE == 0)
                    ((float*)Cout)[(size_t)row * N + cc] = vvv;
                else if (MODE == 1)
                    ((short*)Cout)[(size_t)row * N + cc] = f2bs(vvv);
                else
                    ((short*)Cout)[(size_t)row * N + cc] =
                        f2bs(1.f / (1.f + __expf(-vvv)));
            }
        }
    }
}

// ---------------------------------------------------------------------------
// wkv_chunked: chunked-parallel stable WKV scan; r is PRE-SIGMOIDED bf16.
// ---------------------------------------------------------------------------
__global__ __launch_bounds__(1024) void wkv_chunked(
    const short* __restrict__ kb, const short* __restrict__ vb,
    const short* __restrict__ srb,
    const float* __restrict__ w, const float* __restrict__ u,
    short* __restrict__ rwkv)
{
    __shared__ float sp[NC][CSUB];
    __shared__ float sq[NC][CSUB];
    __shared__ float so[NC][CSUB];

    int tid = threadIdx.x;
    int cl  = tid & (CSUB - 1);
    int ch  = tid >> 5;                 // chunk index 0..NC-1
    int b   = blockIdx.x >> 5;          // grid = Bb * (Cdim/CSUB) = 8*32
    int cg  = blockIdx.x & 31;
    int c   = cg * CSUB + cl;

    float wexp = -__expf(w[c]);
    float uu   = u[c];
    size_t coff = (size_t)b * Tt * Cdim + (size_t)(ch * LCH) * Cdim + c;

    // ---- phase 1: local chunk summary from zero state ----
    float p = 0.f, q = 0.f, o = -1e30f;
    #pragma unroll 8
    for (int t = 0; t < LCH; ++t) {
        size_t off = coff + (size_t)t * Cdim;
        float kt = bs2f(kb[off]);
        float vt = bs2f(vb[off]);
        float wo  = wexp + o;
        float no  = fmaxf(wo, kt);
        float A   = __expf(wo - no);
        float B2  = __expf(kt - no);
        p = A * p + B2 * vt;
        q = A * q + B2;
        o = no;
    }
    sp[ch][cl] = p; sq[ch][cl] = q; so[ch][cl] = o;
    __syncthreads();

    // ---- phase 2: exclusive combine-scan over chunks (1 thread / channel) ----
    if (tid < CSUB) {
        float Ld = wexp * (float)LCH;   // decay of o over a full chunk
        float cp = 0.f, cq = 0.f, co = -1e30f;
        for (int j = 0; j < NC; ++j) {
            float lp = sp[j][tid], lq = sq[j][tid], lo = so[j][tid];
            sp[j][tid] = cp; sq[j][tid] = cq; so[j][tid] = co;  // incoming state
            float od = co + Ld;
            float no = fmaxf(od, lo);
            float A  = __expf(od - no);
            float B2 = __expf(lo - no);
            cp = A * cp + B2 * lp;
            cq = A * cq + B2 * lq;
            co = no;
        }
    }
    __syncthreads();

    // ---- phase 3: outputs from incoming state ----
    p = sp[ch][cl]; q = sq[ch][cl]; o = so[ch][cl];
    #pragma unroll 4
    for (int t = 0; t < LCH; ++t) {
        size_t off = coff + (size_t)t * Cdim;
        float kt = bs2f(kb[off]);
        float vt = bs2f(vb[off]);
        float sr = bs2f(srb[off]);       // sigmoid already applied in GEMM

        float uk  = uu + kt;
        float no  = fmaxf(o, uk);
        float Aa  = __expf(o - no);
        float Bc  = __expf(uk - no);
        float out = (Aa * p + Bc * vt) / (Aa * q + Bc);

        float wo  = wexp + o;
        float no2 = fmaxf(wo, kt);
        float A2  = __expf(wo - no2);
        float B2  = __expf(kt - no2);
        p = A2 * p + B2 * vt;
        q = A2 * q + B2;
        o = no2;

        rwkv[off] = f2bs(sr * out);
    }
}

// ---------------------------------------------------------------------------
extern "C" void kernel_launch(void* const* d_in, const int* in_sizes, int n_in,
                              void* d_out, int out_size, void* d_ws, size_t ws_size,
                              hipStream_t stream)
{
    const float* x    = (const float*)d_in[0];
    const float* w    = (const float*)d_in[1];
    const float* u    = (const float*)d_in[2];
    const float* mixk = (const float*)d_in[3];
    const float* mixv = (const float*)d_in[4];
    const float* mixr = (const float*)d_in[5];
    const float* Wk   = (const float*)d_in[6];
    const float* Wv   = (const float*)d_in[7];
    const float* Wr   = (const float*)d_in[8];
    const float* Wo   = (const float*)d_in[9];

    const size_t SLAB = (size_t)BT * Cdim;           // 16.78M elements
    char* ws = (char*)d_ws;
    short* xmix = (short*)ws;                        // 3 slabs bf16 = 96 MiB
    short* wbf  = (short*)(ws + 3 * SLAB * 2);       // 4*C*C bf16 = 8 MiB
    short* rbuf = (short*)(ws + 3 * SLAB * 2 + (size_t)4 * Cdim * Cdim * 2); // 32 MiB
    short* rwkv = (short*)ws;                        // reuses dead xmix slab 0
    short* kbuf = (short*)d_out;                     // k,v bf16 live in d_out
    short* vbuf = kbuf + SLAB;                       // exactly fills 64 MiB

    prep_x<<<BT * Cdim / 8 / 256, 256, 0, stream>>>(x, mixk, mixv, mixr, xmix);
    prep_w<<<4 * Cdim * Cdim / 8 / 256, 256, 0, stream>>>(Wk, Wv, Wr, Wo, wbf);

    dim3 g2(Cdim / 256, BT / 256);   // (4, 64) = 256 workgroups
    gemm256<1><<<g2, 512, 0, stream>>>(xmix,            wbf,                   kbuf, BT, Cdim, Cdim);
    gemm256<1><<<g2, 512, 0, stream>>>(xmix + SLAB,     wbf + Cdim * Cdim,     vbuf, BT, Cdim, Cdim);
    gemm256<2><<<g2, 512, 0, stream>>>(xmix + 2 * SLAB, wbf + 2 * Cdim * Cdim, rbuf, BT, Cdim, Cdim);

    wkv_chunked<<<Bb * (Cdim / CSUB), 1024, 0, stream>>>(kbuf, vbuf, rbuf, w, u, rwkv);

    gemm256<0><<<g2, 512, 0, stream>>>(rwkv, wbf + 3 * Cdim * Cdim, (float*)d_out, BT, Cdim, Cdim);
}